// Round 2
// baseline (459.364 us; speedup 1.0000x reference)
//
#include <hip/hip_runtime.h>

typedef _Float16 f16;
typedef _Float16 f16x4 __attribute__((ext_vector_type(4)));
typedef _Float16 f16x8 __attribute__((ext_vector_type(8)));
typedef float    f32x4 __attribute__((ext_vector_type(4)));
typedef unsigned int u32;

#define NROWS 65536
#define DDIM  512
#define BM 128
#define BN 128
#define BK 64

// async 16B global->LDS (wave-uniform base + lane*16 layout — LDS must be
// unpadded and laid out in exactly the order lanes compute their dest).
__device__ __forceinline__ void gload_lds16(const void* g, void* l) {
  __builtin_amdgcn_global_load_lds(
      (const __attribute__((address_space(1))) u32*)g,
      (__attribute__((address_space(3))) u32*)l, 16, 0, 0);
}

// ---------------------------------------------------------------------------
// K0a: A fp32 -> f16 (ws). 65536x512. 8 elems/thread, float4 loads.
// ---------------------------------------------------------------------------
__global__ __launch_bounds__(256) void k_cast(const float* __restrict__ A,
                                              f16* __restrict__ Ah) {
  const size_t i = ((size_t)blockIdx.x * 256 + threadIdx.x) * 8;
  const float4 v0 = *(const float4*)(A + i);
  const float4 v1 = *(const float4*)(A + i + 4);
  f16x8 h = {(f16)v0.x, (f16)v0.y, (f16)v0.z, (f16)v0.w,
             (f16)v1.x, (f16)v1.y, (f16)v1.z, (f16)v1.w};
  *(f16x8*)(Ah + i) = h;
}

// ---------------------------------------------------------------------------
// K0b: W [k][n] fp32 -> Wt [n][k] f16 (k-contiguous for B staging).
// ---------------------------------------------------------------------------
__global__ __launch_bounds__(1024) void k_transpose(const float* __restrict__ W,
                                                    f16* __restrict__ Wt) {
  __shared__ float t[32][33];
  const int tx = threadIdx.x, ty = threadIdx.y;
  const int n0 = blockIdx.x * 32, k0 = blockIdx.y * 32;
  t[ty][tx] = W[(size_t)(k0 + ty) * DDIM + n0 + tx];
  __syncthreads();
  Wt[(size_t)(n0 + ty) * DDIM + k0 + tx] = (f16)t[tx][ty];
}

// ---------------------------------------------------------------------------
// K1: feature = A @ W (f16 MFMA), fused ghost-BN + priors. m97-style staging:
// global_load_lds dwordx4, unpadded LDS, BK=64 (2 MFMA K-substeps per stage).
// One block = one ghost batch (128 rows) x 128 cols -> BN stats in-block.
// ---------------------------------------------------------------------------
__global__ __launch_bounds__(256) void k_gemm_bn(const f16*  __restrict__ Ah,
                                                 const float* __restrict__ priors,
                                                 const f16*  __restrict__ Bt,
                                                 const float* __restrict__ gamma,
                                                 const float* __restrict__ beta,
                                                 float* __restrict__ Z) {
  __shared__ __align__(16) f16 Al[BM][BK];   // 16 KB, unpadded (load-order layout)
  __shared__ __align__(16) f16 Bl[BN][BK];   // 16 KB
  __shared__ float2 part[2][BN];
  __shared__ float2 sb[BN];

  const int m0 = blockIdx.y * BM;
  const int c0 = blockIdx.x * BN;
  const int tid  = threadIdx.x;
  const int lane = tid & 63;
  const int wid  = tid >> 6;
  const int wm = wid >> 1, wn = wid & 1;     // 2x2 waves, 64x64 tile each
  const int lr = lane & 15;
  const int lq = lane >> 4;

  f32x4 acc[4][4];
#pragma unroll
  for (int i = 0; i < 4; ++i)
#pragma unroll
    for (int j = 0; j < 4; ++j) acc[i][j] = (f32x4){0.f, 0.f, 0.f, 0.f};

  for (int ks = 0; ks < DDIM / BK; ++ks) {   // 8 K-steps
    const int kb = ks * BK;
    // stage A: 128 rows x 128 B = 1024 x 16B chunks, 4 per thread
#pragma unroll
    for (int r = 0; r < 4; ++r) {
      const int c = tid + r * 256;
      const int row = c >> 3, kp = c & 7;    // 8 chunks per row
      gload_lds16(Ah + (size_t)(m0 + row) * DDIM + kb + kp * 8, (char*)Al + c * 16);
    }
    // stage B: same shape from Wt
#pragma unroll
    for (int r = 0; r < 4; ++r) {
      const int c = tid + r * 256;
      const int col = c >> 3, kp = c & 7;
      gload_lds16(Bt + (size_t)(c0 + col) * DDIM + kb + kp * 8, (char*)Bl + c * 16);
    }
    __syncthreads();                          // drains vmcnt (lds) + barrier
#pragma unroll
    for (int s = 0; s < 2; ++s) {
      f16x8 af[4], bf[4];
#pragma unroll
      for (int mi = 0; mi < 4; ++mi)
        af[mi] = *(const f16x8*)(&Al[wm * 64 + mi * 16 + lr][s * 32 + lq * 8]);
#pragma unroll
      for (int ni = 0; ni < 4; ++ni)
        bf[ni] = *(const f16x8*)(&Bl[wn * 64 + ni * 16 + lr][s * 32 + lq * 8]);
#pragma unroll
      for (int mi = 0; mi < 4; ++mi)
#pragma unroll
        for (int ni = 0; ni < 4; ++ni)
          acc[mi][ni] = __builtin_amdgcn_mfma_f32_16x16x32_f16(af[mi], bf[ni], acc[mi][ni], 0, 0, 0);
    }
    __syncthreads();
  }

  // --- ghost-BN stats (columns complete within block) ---
  // C/D: col = lane&15, row = lq*4 + r within each 16x16 tile
#pragma unroll
  for (int ni = 0; ni < 4; ++ni) {
    float ps = 0.f, pq = 0.f;
#pragma unroll
    for (int mi = 0; mi < 4; ++mi)
#pragma unroll
      for (int r = 0; r < 4; ++r) {
        const float v = acc[mi][ni][r];
        ps += v; pq += v * v;
      }
    ps += __shfl_xor(ps, 16); ps += __shfl_xor(ps, 32);
    pq += __shfl_xor(pq, 16); pq += __shfl_xor(pq, 32);
    if (lq == 0) part[wm][wn * 64 + ni * 16 + lr] = make_float2(ps, pq);
  }
  __syncthreads();
  if (tid < BN) {
    const int c = tid;
    const float sum = part[0][c].x + part[1][c].x;
    const float ssq = part[0][c].y + part[1][c].y;
    const float mean = sum * (1.f / 128.f);
    const float var  = ssq * (1.f / 128.f) - mean * mean;
    const float rstd = rsqrtf(var + 1e-3f);
    const float s = rstd * gamma[c0 + c];
    const float b = beta[c0 + c] - mean * s;
    sb[c] = make_float2(s, b);
  }
  __syncthreads();

  // --- apply BN + priors, write z (fp32) ---
#pragma unroll
  for (int ni = 0; ni < 4; ++ni) {
    const int c = wn * 64 + ni * 16 + lr;
    const float2 s_b = sb[c];
#pragma unroll
    for (int mi = 0; mi < 4; ++mi)
#pragma unroll
      for (int r = 0; r < 4; ++r) {
        const int row = wm * 64 + mi * 16 + lq * 4 + r;
        const size_t off = (size_t)(m0 + row) * DDIM + c0 + c;
        const float z = acc[mi][ni][r] * s_b.x + s_b.y;
        Z[off] = z * priors[off];
      }
  }
}

// ---------------------------------------------------------------------------
// K2: sparsemax per row, in place. One wave per row, 8 vals/lane.
// Classic Michelot: MONOTONE removal (active bitmask, never re-add) ->
// tau non-decreasing -> no oscillation; break when nothing removed.
// ---------------------------------------------------------------------------
__device__ __forceinline__ float wave_sum(float v) {
  v += __shfl_xor(v, 1);  v += __shfl_xor(v, 2);  v += __shfl_xor(v, 4);
  v += __shfl_xor(v, 8);  v += __shfl_xor(v, 16); v += __shfl_xor(v, 32);
  return v;
}

__global__ __launch_bounds__(256) void k_sparsemax(float* __restrict__ Z) {
  const int lane = threadIdx.x & 63;
  const int wid  = threadIdx.x >> 6;
  const int row  = blockIdx.x * 4 + wid;
  float* zr = Z + (size_t)row * DDIM + lane * 8;

  float z[8];
  {
    const float4 v0 = *(const float4*)(zr);
    const float4 v1 = *(const float4*)(zr + 4);
    z[0] = v0.x; z[1] = v0.y; z[2] = v0.z; z[3] = v0.w;
    z[4] = v1.x; z[5] = v1.y; z[6] = v1.z; z[7] = v1.w;
  }

  float S = wave_sum(z[0] + z[1] + z[2] + z[3] + z[4] + z[5] + z[6] + z[7]);
  float C = 512.f;
  float tau = (S - 1.f) * (1.f / 512.f);
  u32 act = 0xFFu;

  for (int it = 0; it < 64; ++it) {
    float rs = 0.f, rc = 0.f;
#pragma unroll
    for (int j = 0; j < 8; ++j) {
      if ((act >> j) & 1u) {
        if (z[j] <= tau) { rs += z[j]; rc += 1.f; act &= ~(1u << j); }
      }
    }
    rs = wave_sum(rs);
    rc = wave_sum(rc);
    if (rc == 0.f) break;          // support stable -> exact fixed point
    S -= rs; C -= rc;
    tau = (S - 1.f) / C;
  }
  // removed elems have z <= some earlier tau <= tau_final -> fmax clips to 0.

  float4 o0, o1;
  o0.x = fmaxf(z[0] - tau, 0.f); o0.y = fmaxf(z[1] - tau, 0.f);
  o0.z = fmaxf(z[2] - tau, 0.f); o0.w = fmaxf(z[3] - tau, 0.f);
  o1.x = fmaxf(z[4] - tau, 0.f); o1.y = fmaxf(z[5] - tau, 0.f);
  o1.z = fmaxf(z[6] - tau, 0.f); o1.w = fmaxf(z[7] - tau, 0.f);
  *(float4*)(zr)     = o0;
  *(float4*)(zr + 4) = o1;
}

// ---------------------------------------------------------------------------
extern "C" void kernel_launch(void* const* d_in, const int* in_sizes, int n_in,
                              void* d_out, int out_size, void* d_ws, size_t ws_size,
                              hipStream_t stream) {
  const float* inputs = (const float*)d_in[0];
  const float* priors = (const float*)d_in[1];
  const float* W      = (const float*)d_in[2];
  const float* gamma  = (const float*)d_in[3];
  const float* beta   = (const float*)d_in[4];
  float* out = (float*)d_out;

  f16* Wt = (f16*)d_ws;                              // 512 KB
  f16* Ah = (f16*)((char*)d_ws + (1 << 20));         // 64 MB at +1 MB

  hipLaunchKernelGGL(k_cast, dim3(NROWS * DDIM / (256 * 8)), dim3(256), 0, stream, inputs, Ah);
  hipLaunchKernelGGL(k_transpose, dim3(DDIM / 32, DDIM / 32), dim3(32, 32), 0, stream, W, Wt);
  hipLaunchKernelGGL(k_gemm_bn, dim3(DDIM / BN, NROWS / BM), dim3(256), 0, stream,
                     Ah, priors, Wt, gamma, beta, out);
  hipLaunchKernelGGL(k_sparsemax, dim3(NROWS / 4), dim3(256), 0, stream, out);
}

// Round 3
// 430.687 us; speedup vs baseline: 1.0666x; 1.0666x over previous
//
#include <hip/hip_runtime.h>

typedef _Float16 f16;
typedef _Float16 f16x8 __attribute__((ext_vector_type(8)));
typedef float    f32x4 __attribute__((ext_vector_type(4)));
typedef unsigned int u32;

#define NROWS 65536
#define DDIM  512
#define BM 128
#define BN 128
#define BK 64

// async 16B global->LDS: dest = wave-uniform base + lane*16 (no scatter).
__device__ __forceinline__ void gload_lds16(const void* g, void* l) {
  __builtin_amdgcn_global_load_lds(
      (const __attribute__((address_space(1))) u32*)g,
      (__attribute__((address_space(3))) u32*)l, 16, 0, 0);
}

// XOR-swizzle: within each 8-chunk (128 B) group along k, chunk kp of row r
// is stored at kp ^ (r&7). The gemm's linear global_load_lds then produces a
// swizzled LDS image whose fragment reads are bank-conflict-free (2-way max).

// ---------------------------------------------------------------------------
// K0a: A fp32 -> f16 swizzled. One 16B chunk (8 f16) per thread.
// ---------------------------------------------------------------------------
__global__ __launch_bounds__(256) void k_cast(const float* __restrict__ A,
                                              f16* __restrict__ Ah) {
  const size_t ci = (size_t)blockIdx.x * 256 + threadIdx.x;  // chunk index
  const size_t i  = ci * 8;
  const int row = (int)(i >> 9);
  const int kp  = (int)(i >> 3) & 63;
  const int kps = (kp & ~7) | ((kp & 7) ^ (row & 7));
  const float4 v0 = *(const float4*)(A + i);
  const float4 v1 = *(const float4*)(A + i + 4);
  f16x8 h = {(f16)v0.x, (f16)v0.y, (f16)v0.z, (f16)v0.w,
             (f16)v1.x, (f16)v1.y, (f16)v1.z, (f16)v1.w};
  *(f16x8*)(Ah + (size_t)row * DDIM + kps * 8) = h;
}

// ---------------------------------------------------------------------------
// K0b: W [k][n] fp32 -> Wt [n][k] f16, k-contiguous, same chunk swizzle by n.
// ---------------------------------------------------------------------------
__global__ __launch_bounds__(1024) void k_transpose(const float* __restrict__ W,
                                                    f16* __restrict__ Wt) {
  __shared__ float t[32][33];
  const int tx = threadIdx.x, ty = threadIdx.y;
  const int n0 = blockIdx.x * 32, k0 = blockIdx.y * 32;
  t[ty][tx] = W[(size_t)(k0 + ty) * DDIM + n0 + tx];
  __syncthreads();
  const int n = n0 + ty, k = k0 + tx;
  const int kp  = k >> 3;
  const int kps = (kp & ~7) | ((kp & 7) ^ (n & 7));
  Wt[(size_t)n * DDIM + kps * 8 + (k & 7)] = (f16)t[tx][ty];
}

// ---------------------------------------------------------------------------
// K1: feature = A @ W (f16 MFMA, fp32 acc), fused ghost-BN + priors.
// m97 staging (global_load_lds x16, unpadded LDS) + XOR-swizzled chunks.
// One block = one ghost batch (128 rows) x 128 cols.
// ---------------------------------------------------------------------------
__global__ __launch_bounds__(256) void k_gemm_bn(const f16*  __restrict__ Ah,
                                                 const float* __restrict__ priors,
                                                 const f16*  __restrict__ Bt,
                                                 const float* __restrict__ gamma,
                                                 const float* __restrict__ beta,
                                                 float* __restrict__ Z) {
  __shared__ __align__(16) f16 Al[BM][BK];   // 16 KB, swizzled image
  __shared__ __align__(16) f16 Bl[BN][BK];   // 16 KB
  __shared__ float2 part[2][BN];
  __shared__ float2 sb[BN];

  const int m0 = blockIdx.y * BM;
  const int c0 = blockIdx.x * BN;
  const int tid  = threadIdx.x;
  const int lane = tid & 63;
  const int wid  = tid >> 6;
  const int wm = wid >> 1, wn = wid & 1;     // 2x2 waves, 64x64 tile each
  const int lr = lane & 15;
  const int lq = lane >> 4;

  f32x4 acc[4][4];
#pragma unroll
  for (int i = 0; i < 4; ++i)
#pragma unroll
    for (int j = 0; j < 4; ++j) acc[i][j] = (f32x4){0.f, 0.f, 0.f, 0.f};

  for (int ks = 0; ks < DDIM / BK; ++ks) {   // 8 K-steps
    const int kb = ks * BK;
    // stage A: 128 rows x 8 chunks = 1024 chunks, 4/thread (linear copy;
    // source is already swizzled within each 8-chunk group)
#pragma unroll
    for (int r = 0; r < 4; ++r) {
      const int c = tid + r * 256;
      const int row = c >> 3, kp = c & 7;
      gload_lds16(Ah + (size_t)(m0 + row) * DDIM + kb + kp * 8, (char*)Al + c * 16);
    }
#pragma unroll
    for (int r = 0; r < 4; ++r) {
      const int c = tid + r * 256;
      const int col = c >> 3, kp = c & 7;
      gload_lds16(Bt + (size_t)(c0 + col) * DDIM + kb + kp * 8, (char*)Bl + c * 16);
    }
    __syncthreads();
#pragma unroll
    for (int s = 0; s < 2; ++s) {
      const int cSw = (s * 4 + lq) ^ (lr & 7);   // de-swizzle chunk select
      f16x8 af[4], bf[4];
#pragma unroll
      for (int mi = 0; mi < 4; ++mi)
        af[mi] = *(const f16x8*)(&Al[wm * 64 + mi * 16 + lr][cSw * 8]);
#pragma unroll
      for (int ni = 0; ni < 4; ++ni)
        bf[ni] = *(const f16x8*)(&Bl[wn * 64 + ni * 16 + lr][cSw * 8]);
#pragma unroll
      for (int mi = 0; mi < 4; ++mi)
#pragma unroll
        for (int ni = 0; ni < 4; ++ni)
          acc[mi][ni] = __builtin_amdgcn_mfma_f32_16x16x32_f16(af[mi], bf[ni], acc[mi][ni], 0, 0, 0);
    }
    __syncthreads();
  }

  // --- ghost-BN stats (columns complete within block) ---
#pragma unroll
  for (int ni = 0; ni < 4; ++ni) {
    float ps = 0.f, pq = 0.f;
#pragma unroll
    for (int mi = 0; mi < 4; ++mi)
#pragma unroll
      for (int r = 0; r < 4; ++r) {
        const float v = acc[mi][ni][r];
        ps += v; pq += v * v;
      }
    ps += __shfl_xor(ps, 16); ps += __shfl_xor(ps, 32);
    pq += __shfl_xor(pq, 16); pq += __shfl_xor(pq, 32);
    if (lq == 0) part[wm][wn * 64 + ni * 16 + lr] = make_float2(ps, pq);
  }
  __syncthreads();
  if (tid < BN) {
    const int c = tid;
    const float sum = part[0][c].x + part[1][c].x;
    const float ssq = part[0][c].y + part[1][c].y;
    const float mean = sum * (1.f / 128.f);
    const float var  = ssq * (1.f / 128.f) - mean * mean;
    const float rstd = rsqrtf(var + 1e-3f);
    const float s = rstd * gamma[c0 + c];
    const float b = beta[c0 + c] - mean * s;
    sb[c] = make_float2(s, b);
  }
  __syncthreads();

  // --- apply BN + priors, write z (fp32) ---
#pragma unroll
  for (int ni = 0; ni < 4; ++ni) {
    const int c = wn * 64 + ni * 16 + lr;
    const float2 s_b = sb[c];
#pragma unroll
    for (int mi = 0; mi < 4; ++mi)
#pragma unroll
      for (int r = 0; r < 4; ++r) {
        const int row = wm * 64 + mi * 16 + lq * 4 + r;
        const size_t off = (size_t)(m0 + row) * DDIM + c0 + c;
        const float z = acc[mi][ni][r] * s_b.x + s_b.y;
        Z[off] = z * priors[off];
      }
  }
}

// ---------------------------------------------------------------------------
// K2: sparsemax v3 — 8 lanes per row, 64 vals/lane. Group reductions need
// only shfl_xor{1,2,4} (3 DS ops vs 6), 8 rows per wave in parallel -> 16x
// less shuffle traffic than wave-per-row. Knocked-out elems set to -1e30
// (monotone Michelot, no mask). Element order within a row is irrelevant
// (simplex projection is permutation-invariant), so lanes own interleaved
// float4 chunks for coalescing.
// ---------------------------------------------------------------------------
__global__ __launch_bounds__(256) void k_sparsemax(float* __restrict__ Z) {
  const int lane = threadIdx.x & 63;
  const int wid  = threadIdx.x >> 6;
  const int g    = lane >> 3;          // row within wave (0..7)
  const int l3   = lane & 7;           // lane within row group
  const int row  = blockIdx.x * 32 + wid * 8 + g;
  float* base = Z + (size_t)row * DDIM;

  float z[64];
#pragma unroll
  for (int k = 0; k < 16; ++k) {
    const float4 v = *(const float4*)(base + (l3 + 8 * k) * 4);
    z[4 * k]     = v.x; z[4 * k + 1] = v.y;
    z[4 * k + 2] = v.z; z[4 * k + 3] = v.w;
  }

  float s = 0.f;
#pragma unroll
  for (int j = 0; j < 64; ++j) s += z[j];
  s += __shfl_xor(s, 1); s += __shfl_xor(s, 2); s += __shfl_xor(s, 4);

  float tau = (s - 1.f) * (1.f / 512.f);
  float rcprev = 512.f;

  for (int it = 0; it < 40; ++it) {
    float rs = 0.f, rc = 0.f;
#pragma unroll
    for (int j = 0; j < 64; ++j) {
      const bool a = z[j] > tau;
      rs += a ? z[j] : 0.f;
      rc += a ? 1.f : 0.f;
      z[j] = a ? z[j] : -1e30f;        // knock out (monotone: tau never decreases)
    }
    rs += __shfl_xor(rs, 1); rs += __shfl_xor(rs, 2); rs += __shfl_xor(rs, 4);
    rc += __shfl_xor(rc, 1); rc += __shfl_xor(rc, 2); rc += __shfl_xor(rc, 4);
    const bool changed = (rc != rcprev);
    rcprev = rc;
    tau = (rs - 1.f) / fmaxf(rc, 1.f);
    if (!__any(changed)) break;        // all 8 row-groups in this wave stable
  }

#pragma unroll
  for (int k = 0; k < 16; ++k) {
    float4 o;
    o.x = fmaxf(z[4 * k]     - tau, 0.f);
    o.y = fmaxf(z[4 * k + 1] - tau, 0.f);
    o.z = fmaxf(z[4 * k + 2] - tau, 0.f);
    o.w = fmaxf(z[4 * k + 3] - tau, 0.f);
    *(float4*)(base + (l3 + 8 * k) * 4) = o;
  }
}

// ---------------------------------------------------------------------------
extern "C" void kernel_launch(void* const* d_in, const int* in_sizes, int n_in,
                              void* d_out, int out_size, void* d_ws, size_t ws_size,
                              hipStream_t stream) {
  const float* inputs = (const float*)d_in[0];
  const float* priors = (const float*)d_in[1];
  const float* W      = (const float*)d_in[2];
  const float* gamma  = (const float*)d_in[3];
  const float* beta   = (const float*)d_in[4];
  float* out = (float*)d_out;

  f16* Wt = (f16*)d_ws;                              // 512 KB
  f16* Ah = (f16*)((char*)d_ws + (1 << 20));         // 64 MB at +1 MB

  hipLaunchKernelGGL(k_cast, dim3(NROWS * DDIM / (256 * 8)), dim3(256), 0, stream, inputs, Ah);
  hipLaunchKernelGGL(k_transpose, dim3(DDIM / 32, DDIM / 32), dim3(32, 32), 0, stream, W, Wt);
  hipLaunchKernelGGL(k_gemm_bn, dim3(DDIM / BN, NROWS / BM), dim3(256), 0, stream,
                     Ah, priors, Wt, gamma, beta, out);
  hipLaunchKernelGGL(k_sparsemax, dim3(NROWS / 32), dim3(256), 0, stream, out);
}

// Round 4
// 382.617 us; speedup vs baseline: 1.2006x; 1.1256x over previous
//
#include <hip/hip_runtime.h>

typedef _Float16 f16;
typedef _Float16 f16x4v __attribute__((ext_vector_type(4)));
typedef _Float16 f16x8 __attribute__((ext_vector_type(8)));
typedef float    f32x4 __attribute__((ext_vector_type(4)));
typedef unsigned int u32;

#define NROWS 65536
#define DDIM  512
#define BM    128     // rows per block = one ghost batch
#define BK    32
#define ZP    516     // zbuf row pitch (floats): 2064 B -> bank-spread reads

// async 16B global->LDS: dest must be wave-uniform base + lane*16.
__device__ __forceinline__ void gload_lds16(const void* g, void* l) {
  __builtin_amdgcn_global_load_lds(
      (const __attribute__((address_space(1))) u32*)g,
      (__attribute__((address_space(3))) u32*)l, 16, 0, 0);
}

__device__ __forceinline__ float wave_sum64(float v) {
  v += __shfl_xor(v, 1);  v += __shfl_xor(v, 2);  v += __shfl_xor(v, 4);
  v += __shfl_xor(v, 8);  v += __shfl_xor(v, 16); v += __shfl_xor(v, 32);
  return v;
}

// ---------------------------------------------------------------------------
// K0: W [k][n] fp32 -> Wt [n][k] f16, k-contiguous, 2-bit chunk XOR-swizzle
// (chunk kp of row n stored at (kp&~3)|((kp&3)^(n&3)) within each 32-k group)
// so the fused kernel's linear global_load_lds lands a conflict-free image.
// ---------------------------------------------------------------------------
__global__ __launch_bounds__(1024) void k_transpose(const float* __restrict__ W,
                                                    f16* __restrict__ Wt) {
  __shared__ float t[32][33];
  const int tx = threadIdx.x, ty = threadIdx.y;
  const int n0 = blockIdx.x * 32, k0 = blockIdx.y * 32;
  t[ty][tx] = W[(size_t)(k0 + ty) * DDIM + n0 + tx];
  __syncthreads();
  const int n = n0 + ty, k = k0 + tx;
  const int kp  = k >> 3;
  const int kps = (kp & ~3) | ((kp & 3) ^ (n & 3));
  Wt[(size_t)n * DDIM + kps * 8 + (k & 7)] = (f16)t[tx][ty];
}

// ---------------------------------------------------------------------------
// K1: fully fused  out = sparsemax( ghostBN(A @ W) * priors ).
// Block: 128 rows x 512 cols (BN stats AND sparsemax rows complete in-block).
// 1024 threads = 16 waves; wave tile 128x32 -> column stats in-wave (2 shfl).
// K-loop: f16 MFMA 16x16x32, A staged with inline fp32->f16 convert (read
// once, no cast kernel), B via global_load_lds from pre-swizzled Wt.
// Epilogue: 8 passes of 16 rows through f32 LDS transpose buffer; priors/out
// accessed as fully-coalesced float4 rows; wave-per-row monotone Michelot.
// ---------------------------------------------------------------------------
__global__ __launch_bounds__(1024, 4) void k_fused(
    const float* __restrict__ A, const float* __restrict__ priors,
    const f16*  __restrict__ Bt, const float* __restrict__ gamma,
    const float* __restrict__ beta, float* __restrict__ Out) {
  __shared__ __align__(16) char smem[40960];
  f16*   Al = (f16*)smem;              // [128][32] = 8 KB  (staging)
  f16*   Bl = (f16*)(smem + 8192);     // [512][32] = 32 KB (staging)
  float* zb = (float*)smem;            // [16][516] = 33 KB (epilogue, reuses)

  const int tid  = threadIdx.x;
  const int lane = tid & 63;
  const int wid  = tid >> 6;           // 0..15: wave = 32-col slice
  const int lr   = lane & 15;
  const int lq   = lane >> 4;
  const int m0   = blockIdx.x * BM;

  // A staging map: thread -> (row, 4-float half-chunk), swizzled LDS dest
  const int arow = tid >> 3;           // 0..127
  const int aq   = tid & 7;            // half-chunk (4 floats)
  const int akps = (aq >> 1) ^ (arow & 3);
  const float* ap = A + (size_t)(m0 + arow) * DDIM + aq * 4;
  f16* adst = Al + arow * BK + akps * 8 + (aq & 1) * 4;

  f32x4 acc[8][2];
#pragma unroll
  for (int mi = 0; mi < 8; ++mi)
#pragma unroll
    for (int ni = 0; ni < 2; ++ni) acc[mi][ni] = (f32x4){0.f, 0.f, 0.f, 0.f};

  for (int ks = 0; ks < DDIM / BK; ++ks) {   // 16 K-steps
    const int kb = ks * BK;
    // B: 512 cols x 32 k = 2048 x 16B chunks, 2/thread, async DMA
#pragma unroll
    for (int r = 0; r < 2; ++r) {
      const int c = tid + r * 1024;
      const int col = c >> 2, kp = c & 3;
      gload_lds16(Bt + (size_t)col * DDIM + kb + kp * 8, (char*)Bl + c * 16);
    }
    // A: fp32 float4 -> f16x4, swizzled ds_write
    const float4 av = *(const float4*)(ap + kb);
    f16x4v hv = {(f16)av.x, (f16)av.y, (f16)av.z, (f16)av.w};
    *(f16x4v*)adst = hv;
    __syncthreads();

    const int cs = lq ^ (lr & 3);            // de-swizzle chunk select
    const f16x8 bf0 = *(const f16x8*)(Bl + (size_t)(wid * 32 + lr) * BK + cs * 8);
    const f16x8 bf1 = *(const f16x8*)(Bl + (size_t)(wid * 32 + 16 + lr) * BK + cs * 8);
#pragma unroll
    for (int mi = 0; mi < 8; ++mi) {
      const f16x8 af = *(const f16x8*)(Al + (size_t)(mi * 16 + lr) * BK + cs * 8);
      acc[mi][0] = __builtin_amdgcn_mfma_f32_16x16x32_f16(af, bf0, acc[mi][0], 0, 0, 0);
      acc[mi][1] = __builtin_amdgcn_mfma_f32_16x16x32_f16(af, bf1, acc[mi][1], 0, 0, 0);
    }
    __syncthreads();
  }

  // --- ghost-BN stats in-wave (wave owns whole columns) + apply ---
  // C/D layout: col = lane&15 (per 16-tile), row = mi*16 + lq*4 + r
#pragma unroll
  for (int ni = 0; ni < 2; ++ni) {
    float ps = 0.f, pq = 0.f;
#pragma unroll
    for (int mi = 0; mi < 8; ++mi)
#pragma unroll
      for (int r = 0; r < 4; ++r) {
        const float v = acc[mi][ni][r];
        ps += v; pq += v * v;
      }
    ps += __shfl_xor(ps, 16); ps += __shfl_xor(ps, 32);  // sum over lq
    pq += __shfl_xor(pq, 16); pq += __shfl_xor(pq, 32);
    const int col = wid * 32 + ni * 16 + lr;
    const float mean = ps * (1.f / 128.f);
    const float var  = pq * (1.f / 128.f) - mean * mean;
    const float rstd = rsqrtf(var + 1e-3f);
    const float s = rstd * gamma[col];
    const float b = beta[col] - mean * s;
#pragma unroll
    for (int mi = 0; mi < 8; ++mi)
#pragma unroll
      for (int r = 0; r < 4; ++r)
        acc[mi][ni][r] = acc[mi][ni][r] * s + b;
  }

  // --- epilogue: 8 passes x 16 rows; LDS transpose -> coalesced sparsemax ---
#pragma unroll
  for (int p = 0; p < 8; ++p) {
    __syncthreads();                         // zb free (prev pass / staging)
    // dump rows p*16..p*16+15 (mi = p): 2-way-max bank aliasing (free)
#pragma unroll
    for (int ni = 0; ni < 2; ++ni)
#pragma unroll
      for (int r = 0; r < 4; ++r)
        zb[(lq * 4 + r) * ZP + wid * 32 + ni * 16 + lr] = acc[p][ni][r];
    __syncthreads();

    // wave `wid` processes local row `wid`: 8 f32/lane, fully coalesced I/O
    const int grow = m0 + p * 16 + wid;
    const float* pr = priors + (size_t)grow * DDIM;
    float* orow = Out + (size_t)grow * DDIM;
    float z[8];
    float S = 0.f;
#pragma unroll
    for (int k = 0; k < 2; ++k) {
      const int cc = (lane + 64 * k) * 4;
      const float4 zv = *(const float4*)(zb + wid * ZP + cc);
      const float4 pv = *(const float4*)(pr + cc);
      z[4 * k]     = zv.x * pv.x; z[4 * k + 1] = zv.y * pv.y;
      z[4 * k + 2] = zv.z * pv.z; z[4 * k + 3] = zv.w * pv.w;
      S += z[4 * k] + z[4 * k + 1] + z[4 * k + 2] + z[4 * k + 3];
    }
    S = wave_sum64(S);
    float tau = (S - 1.f) * (1.f / 512.f);
    float rcprev = 512.f;
    for (int it = 0; it < 40; ++it) {        // monotone Michelot, ~5-8 iters
      float rs = 0.f, rc = 0.f;
#pragma unroll
      for (int j = 0; j < 8; ++j) {
        const bool a = z[j] > tau;
        rs += a ? z[j] : 0.f;
        rc += a ? 1.f : 0.f;
        z[j] = a ? z[j] : -1e30f;            // knock out, never re-admit
      }
      rs = wave_sum64(rs);
      rc = wave_sum64(rc);
      const bool changed = (rc != rcprev);
      rcprev = rc;
      tau = (rs - 1.f) / fmaxf(rc, 1.f);
      if (!__any(changed)) break;
    }
#pragma unroll
    for (int k = 0; k < 2; ++k) {
      const int cc = (lane + 64 * k) * 4;
      float4 o;
      o.x = fmaxf(z[4 * k]     - tau, 0.f);
      o.y = fmaxf(z[4 * k + 1] - tau, 0.f);
      o.z = fmaxf(z[4 * k + 2] - tau, 0.f);
      o.w = fmaxf(z[4 * k + 3] - tau, 0.f);
      *(float4*)(orow + cc) = o;
    }
  }
}

// ---------------------------------------------------------------------------
extern "C" void kernel_launch(void* const* d_in, const int* in_sizes, int n_in,
                              void* d_out, int out_size, void* d_ws, size_t ws_size,
                              hipStream_t stream) {
  const float* inputs = (const float*)d_in[0];
  const float* priors = (const float*)d_in[1];
  const float* W      = (const float*)d_in[2];
  const float* gamma  = (const float*)d_in[3];
  const float* beta   = (const float*)d_in[4];
  float* out = (float*)d_out;
  f16*   Wt  = (f16*)d_ws;                   // 512 KB scratch

  hipLaunchKernelGGL(k_transpose, dim3(DDIM / 32, DDIM / 32), dim3(32, 32), 0, stream, W, Wt);
  hipLaunchKernelGGL(k_fused, dim3(NROWS / BM), dim3(1024), 0, stream,
                     inputs, priors, Wt, gamma, beta, out);
}